// Round 9
// baseline (187.157 us; speedup 1.0000x reference)
//
#include <hip/hip_runtime.h>
#include <math.h>

// WordLabelAttention on MI355X — Round 9: fused attention + output GEMM.
// N=4, H=8, D=64, E=512, KL=512, QROWS/n=2048.
//
//   prep      : blocks 0..511 kv_proj (K->Kp[nh][kl][d], V->Vt[nh][d][kl]);
//               blocks 512..575 convert Wo -> bf16.
//   attn_gemm : grid 512 = (n, 16-q-row tile), block 512 = 8 waves, ONE HEAD
//               PER WAVE. Per wave: fused q-proj (scale folded into Wq,
//               p = exp2(s)), 8 key-tiles with K/V fragments direct from
//               global (L2-hot, 1 MB/n working set), mask bias as MFMA
//               acc-init, P via wave-private LDS rows, deferred
//               normalization. Normalized O^T slice -> shared LDS tile
//               [16][512]; ONE barrier; each wave then computes
//               out[16 x 64cols] = AOt @ Wo_bf^T + bo directly.
//               Removes the AO HBM round-trip + out_gemm dispatch.

typedef __bf16 bf16;
typedef __attribute__((ext_vector_type(8))) __bf16 bf16x8;
typedef __attribute__((ext_vector_type(4))) __bf16 bf16x4;
typedef __attribute__((ext_vector_type(4))) float f32x4;

#define LW 68   // LDS row stride for kv_proj staging
#define LS 72   // LDS row stride for per-wave P/Q scratch (16B-aligned rows)
#define AOW 524 // LDS row stride for the shared AO tile (bank-spread)
#define QSCALE (0.044194173824159216f * 1.4426950408889634f)  // log2(e)/sqrt(512)
#define MASK_BIAS -64.0f

__device__ __forceinline__ bf16x8 cvt8(const float* p, float s) {
    float4 x0 = *(const float4*)p;
    float4 x1 = *(const float4*)(p + 4);
    return (bf16x8){(bf16)(x0.x * s), (bf16)(x0.y * s), (bf16)(x0.z * s), (bf16)(x0.w * s),
                    (bf16)(x1.x * s), (bf16)(x1.y * s), (bf16)(x1.z * s), (bf16)(x1.w * s)};
}

// ---------------------------------------------------------------- prep
// grid 576: [0,512) kv_proj (32 nh x 16 kl-tiles of 32 rows); [512,576) Wo cvt.
__global__ __launch_bounds__(256, 2) void prep(const float* __restrict__ keys,
                                               const float* __restrict__ values,
                                               const float* __restrict__ Wk,
                                               const float* __restrict__ Wv,
                                               const float* __restrict__ Wo,
                                               bf16* __restrict__ Kp,
                                               bf16* __restrict__ Vt,
                                               bf16* __restrict__ Wo_bf) {
    __shared__ bf16 Xk[32 * LW];
    __shared__ bf16 Xv[32 * LW];
    int t = threadIdx.x;
    if (blockIdx.x >= 512) {  // Wo f32 -> bf16: 64 blocks x 256 thr x 16 elems
        int i0 = (blockIdx.x - 512) * 4096 + t * 16;
        *(bf16x8*)(Wo_bf + i0) = cvt8(Wo + i0, 1.0f);
        *(bf16x8*)(Wo_bf + i0 + 8) = cvt8(Wo + i0 + 8, 1.0f);
        return;
    }
    int nh = blockIdx.x >> 4, klt = blockIdx.x & 15;
    int n = nh >> 3, h = nh & 7, kl0 = klt * 32;
    int w = t >> 6, quad = (t >> 4) & 3, c16 = t & 15;
#pragma unroll
    for (int i = 0; i < 2; ++i) {
        int f = t + i * 256, row = f >> 4, c4 = f & 15;
        float4 a = *(const float4*)(keys + ((long)n * 512 + kl0 + row) * 512 + h * 64 + c4 * 4);
        float4 b = *(const float4*)(values + ((long)n * 512 + kl0 + row) * 512 + h * 64 + c4 * 4);
        *(bf16x4*)&Xk[row * LW + c4 * 4] = (bf16x4){(bf16)a.x, (bf16)a.y, (bf16)a.z, (bf16)a.w};
        *(bf16x4*)&Xv[row * LW + c4 * 4] = (bf16x4){(bf16)b.x, (bf16)b.y, (bf16)b.z, (bf16)b.w};
    }
    __syncthreads();
    if (w < 2) {
        // Kp[kl][d] = X @ Wk^T ; wave w owns kl rows 16w..16w+15
        f32x4 acc[4];
#pragma unroll
        for (int nb = 0; nb < 4; ++nb) acc[nb] = (f32x4){0.f, 0.f, 0.f, 0.f};
#pragma unroll
        for (int kc = 0; kc < 2; ++kc) {
            bf16x8 a = *(const bf16x8*)&Xk[(16 * w + c16) * LW + 32 * kc + quad * 8];
#pragma unroll
            for (int nb = 0; nb < 4; ++nb) {
                bf16x8 b = cvt8(Wk + (16 * nb + c16) * 64 + 32 * kc + quad * 8, 1.0f);
                acc[nb] = __builtin_amdgcn_mfma_f32_16x16x32_bf16(a, b, acc[nb], 0, 0, 0);
            }
        }
#pragma unroll
        for (int nb = 0; nb < 4; ++nb)
#pragma unroll
            for (int r = 0; r < 4; ++r)
                Kp[((long)nh * 512 + kl0 + 16 * w + quad * 4 + r) * 64 + 16 * nb + c16] =
                    (bf16)acc[nb][r];
    } else {
        // Vt[d][kl] = Wv @ X^T ; wave w2 owns d 32w2..32w2+31
        int w2 = w - 2;
        f32x4 acc[2][2];
#pragma unroll
        for (int mb = 0; mb < 2; ++mb)
#pragma unroll
            for (int nb = 0; nb < 2; ++nb) acc[mb][nb] = (f32x4){0.f, 0.f, 0.f, 0.f};
#pragma unroll
        for (int kc = 0; kc < 2; ++kc) {
#pragma unroll
            for (int mb = 0; mb < 2; ++mb) {
                bf16x8 a = cvt8(Wv + (32 * w2 + 16 * mb + c16) * 64 + 32 * kc + quad * 8, 1.0f);
#pragma unroll
                for (int nb = 0; nb < 2; ++nb) {
                    bf16x8 b = *(const bf16x8*)&Xv[(16 * nb + c16) * LW + 32 * kc + quad * 8];
                    acc[mb][nb] = __builtin_amdgcn_mfma_f32_16x16x32_bf16(a, b, acc[mb][nb], 0, 0, 0);
                }
            }
        }
#pragma unroll
        for (int mb = 0; mb < 2; ++mb)
#pragma unroll
            for (int nb = 0; nb < 2; ++nb)
#pragma unroll
                for (int r = 0; r < 4; ++r)
                    Vt[((long)nh * 64 + 32 * w2 + 16 * mb + quad * 4 + r) * 512 + kl0 + 16 * nb + c16] =
                        (bf16)acc[mb][nb][r];
    }
}

// ---------------------------------------------------------------- attn_gemm
// grid 512 = 4 n x 128 q-tiles(16 rows). block 512 = 8 waves, wave w = head w.
__global__ __launch_bounds__(512, 4) void attn_gemm(const float* __restrict__ query,
                                                    const float* __restrict__ Wq,
                                                    const bf16* __restrict__ Kp,
                                                    const bf16* __restrict__ Vtg,
                                                    const int* __restrict__ maskp,
                                                    const bf16* __restrict__ Wo_bf,
                                                    const float* __restrict__ bo,
                                                    float* __restrict__ out) {
    __shared__ bf16 PW[128 * LS];   // wave w: rows 16w..16w+15 (Q stage -> Qt -> P)
    __shared__ bf16 AOt[16 * AOW];  // shared [local q-row][E col]
    int t = threadIdx.x;
    int w = t >> 6, quad = (t >> 4) & 3, c16 = t & 15;
    int n = blockIdx.x >> 7, qt = blockIdx.x & 127;
    int r0 = qt * 16;
    int nh = n * 8 + w;
    const bf16* Kb = Kp + (long)nh * 512 * 64;
    const bf16* Vb = Vtg + (long)nh * 64 * 512;
    bf16* Pw = PW + w * 16 * LS;

    // Wq fragments (scale folded); same addresses for all waves -> L1/L2 broadcast
    bf16x8 wf[8];
#pragma unroll
    for (int nb = 0; nb < 4; ++nb)
#pragma unroll
        for (int kc = 0; kc < 2; ++kc)
            wf[nb * 2 + kc] = cvt8(Wq + (16 * nb + c16) * 64 + 32 * kc + quad * 8, QSCALE);

    // stage this wave's 16 query rows, head-w slice (wave-private: no barrier)
    {
        int l = t & 63;
        int rl = l >> 2;
        const float* qrow = query + ((long)n * 2048 + r0 + rl) * 512 + w * 64;
#pragma unroll
        for (int j = 0; j < 4; ++j) {
            int c = (l & 3) + 4 * j;
            float4 a = *(const float4*)(qrow + c * 4);
            *(bf16x4*)&Pw[rl * LS + c * 4] = (bf16x4){(bf16)a.x, (bf16)a.y, (bf16)a.z, (bf16)a.w};
        }
    }
    // q-proj (16 rows): C[row][d]
    f32x4 qa[4];
#pragma unroll
    for (int nb = 0; nb < 4; ++nb) qa[nb] = (f32x4){0.f, 0.f, 0.f, 0.f};
#pragma unroll
    for (int kc = 0; kc < 2; ++kc) {
        bf16x8 a = *(const bf16x8*)&Pw[c16 * LS + 32 * kc + quad * 8];
#pragma unroll
        for (int nb = 0; nb < 4; ++nb)
            qa[nb] = __builtin_amdgcn_mfma_f32_16x16x32_bf16(a, wf[nb * 2 + kc], qa[nb], 0, 0, 0);
    }
    // Qt (C-layout) back into Pw, hoist A-layout Q fragments, then Pw is free for P
#pragma unroll
    for (int nb = 0; nb < 4; ++nb)
#pragma unroll
        for (int r = 0; r < 4; ++r)
            Pw[(quad * 4 + r) * LS + 16 * nb + c16] = (bf16)qa[nb][r];
    bf16x8 qf[2];
#pragma unroll
    for (int kc = 0; kc < 2; ++kc)
        qf[kc] = *(const bf16x8*)&Pw[c16 * LS + 32 * kc + quad * 8];

    f32x4 oacc[4];
#pragma unroll
    for (int mb = 0; mb < 4; ++mb) oacc[mb] = (f32x4){0.f, 0.f, 0.f, 0.f};
    float ps = 0.f;

    for (int kt = 0; kt < 8; ++kt) {
        // mask bias as acc-init (int4 broadcast loads, 16B aligned)
        f32x4 sc[4];
#pragma unroll
        for (int mb = 0; mb < 4; ++mb) {
            int4 mk = *(const int4*)(maskp + n * 512 + kt * 64 + 16 * mb + quad * 4);
            sc[mb] = (f32x4){mk.x ? 0.f : MASK_BIAS, mk.y ? 0.f : MASK_BIAS,
                             mk.z ? 0.f : MASK_BIAS, mk.w ? 0.f : MASK_BIAS};
        }
        // S^T = K.Q^T, K fragments direct from global (L2-hot)
#pragma unroll
        for (int kc = 0; kc < 2; ++kc) {
#pragma unroll
            for (int mb = 0; mb < 4; ++mb) {
                bf16x8 ka = *(const bf16x8*)(Kb + (long)(kt * 64 + 16 * mb + c16) * 64 + 32 * kc + quad * 8);
                sc[mb] = __builtin_amdgcn_mfma_f32_16x16x32_bf16(ka, qf[kc], sc[mb], 0, 0, 0);
            }
        }
        // p = exp2(s); l += p; P into wave-private rows [qrow=c16][key]
#pragma unroll
        for (int mb = 0; mb < 4; ++mb) {
            float p0 = exp2f(sc[mb][0]);
            float p1 = exp2f(sc[mb][1]);
            float p2 = exp2f(sc[mb][2]);
            float p3 = exp2f(sc[mb][3]);
            ps += (p0 + p1) + (p2 + p3);
            *(bf16x4*)&Pw[c16 * LS + 16 * mb + quad * 4] =
                (bf16x4){(bf16)p0, (bf16)p1, (bf16)p2, (bf16)p3};
        }
        // O^T += V.P^T, V fragments direct from global
#pragma unroll
        for (int kc = 0; kc < 2; ++kc) {
            bf16x8 pb = *(const bf16x8*)&Pw[c16 * LS + 32 * kc + quad * 8];
#pragma unroll
            for (int mb = 0; mb < 4; ++mb) {
                bf16x8 va = *(const bf16x8*)(Vb + (long)(16 * mb + c16) * 512 + kt * 64 + 32 * kc + quad * 8);
                oacc[mb] = __builtin_amdgcn_mfma_f32_16x16x32_bf16(va, pb, oacc[mb], 0, 0, 0);
            }
        }
    }
    // normalize and drop this head's slice into the shared AO tile
    ps += __shfl_xor(ps, 16);
    ps += __shfl_xor(ps, 32);
    float il = 1.0f / ps;
#pragma unroll
    for (int mb = 0; mb < 4; ++mb)
        *(bf16x4*)&AOt[c16 * AOW + 64 * w + 16 * mb + quad * 4] =
            (bf16x4){(bf16)(oacc[mb][0] * il), (bf16)(oacc[mb][1] * il),
                     (bf16)(oacc[mb][2] * il), (bf16)(oacc[mb][3] * il)};
    __syncthreads();  // the ONLY block-wide barrier

    // epilogue: out[16 rows x cols 64w..64w+63] = AOt @ Wo_bf^T + bo
    f32x4 acc[4];
#pragma unroll
    for (int nb = 0; nb < 4; ++nb) acc[nb] = (f32x4){0.f, 0.f, 0.f, 0.f};
#pragma unroll
    for (int ch = 0; ch < 16; ++ch) {
        bf16x8 a = *(const bf16x8*)&AOt[c16 * AOW + 32 * ch + 8 * quad];
#pragma unroll
        for (int nb = 0; nb < 4; ++nb) {
            bf16x8 b = *(const bf16x8*)(Wo_bf + (long)(64 * w + 16 * nb + c16) * 512 + 32 * ch + 8 * quad);
            acc[nb] = __builtin_amdgcn_mfma_f32_16x16x32_bf16(a, b, acc[nb], 0, 0, 0);
        }
    }
#pragma unroll
    for (int nb = 0; nb < 4; ++nb) {
        float bias = bo[64 * w + 16 * nb + c16];
#pragma unroll
        for (int r = 0; r < 4; ++r)
            out[(long)(n * 2048 + r0 + quad * 4 + r) * 512 + 64 * w + 16 * nb + c16] =
                acc[nb][r] + bias;
    }
}

extern "C" void kernel_launch(void* const* d_in, const int* in_sizes, int n_in,
                              void* d_out, int out_size, void* d_ws, size_t ws_size,
                              hipStream_t stream) {
    const float* values = (const float*)d_in[0];
    const float* keys   = (const float*)d_in[1];
    const float* query  = (const float*)d_in[2];
    const int*   maskp  = (const int*)d_in[3];
    const float* Wv     = (const float*)d_in[4];
    const float* Wk     = (const float*)d_in[5];
    const float* Wq     = (const float*)d_in[6];
    const float* Wo     = (const float*)d_in[7];
    const float* bo     = (const float*)d_in[8];
    float* out = (float*)d_out;

    bf16* ws = (bf16*)d_ws;
    bf16* Kp    = ws;                 // 1,048,576 bf16
    bf16* Vt    = Kp + 1048576;       // 1,048,576
    bf16* Wo_bf = Vt + 1048576;       // 262,144

    prep<<<dim3(576), dim3(256), 0, stream>>>(keys, values, Wk, Wv, Wo, Kp, Vt, Wo_bf);
    attn_gemm<<<dim3(512), dim3(512), 0, stream>>>(query, Wq, Kp, Vt, maskp, Wo_bf, bo, out);
}